// Round 5
// baseline (384.051 us; speedup 1.0000x reference)
//
#include <hip/hip_runtime.h>
#include <hip/hip_bf16.h>

#define BB 32768
#define NN 10
#define VV 2000
#define EPSBN 1e-5

// ---------------- K0: build T1[v][l][o] = emb[v] . W1[o][16l:16l+16] ----------------
__global__ __launch_bounds__(256) void k_table(const float* __restrict__ emb,
                                               const float* __restrict__ W1,
                                               float* __restrict__ T1) {
  int idx = blockIdx.x * 256 + threadIdx.x;
  if (idx >= VV * 640) return;
  int v = idx / 640;
  int r = idx - v * 640;
  int l = r >> 6;
  int o = r & 63;
  const float* e = emb + v * 16;
  const float* w = W1 + o * 160 + l * 16;
  float s = 0.f;
#pragma unroll
  for (int k = 0; k < 16; ++k) s = fmaf(e[k], w[k], s);
  T1[idx] = s;
}

// ---- K0b: W3T[k][jj] = (w_ih @ W2) transposed, f-gate rows stripped ----
// jj in [0,48): 0-15 -> i rows (w_ih row jj), 16-31 -> g rows (w_ih row jj+16),
// 32-47 -> o rows (w_ih row jj+16). bias3T likewise.
__global__ __launch_bounds__(256) void k_fuse(const float* __restrict__ w_ih,
    const float* __restrict__ b_ih, const float* __restrict__ b_hh,
    const float* __restrict__ W2, const float* __restrict__ b2v,
    float* __restrict__ W3T, float* __restrict__ bias3T) {
  int idx = blockIdx.x * 256 + threadIdx.x;
  if (idx < 3072) {
    int k = idx / 48, jj = idx - k * 48;
    int gr = (jj < 16) ? jj : jj + 16;
    float s = 0.f;
#pragma unroll
    for (int o = 0; o < 16; ++o) s = fmaf(w_ih[gr * 16 + o], W2[o * 64 + k], s);
    W3T[idx] = s;
  } else if (idx < 3120) {
    int jj = idx - 3072;
    int gr = (jj < 16) ? jj : jj + 16;
    float s = b_ih[gr] + b_hh[gr];
#pragma unroll
    for (int o = 0; o < 16; ++o) s = fmaf(w_ih[gr * 16 + o], b2v[o], s);
    bias3T[jj] = s;
  }
}

// ---------------- K1: item-per-lane, no LDS, no cross-lane ----------------
// Round-4 lesson: the old lane-per-channel layout spent ~192 cy/item of LDS
// pipe on 16 broadcast ds_read_b128 (matches measured 111-121us). Here each
// lane owns a whole (b,n) item: h1[64] lane-private in VGPRs, W3T streamed
// through SGPRs (wave-uniform), f-gate skipped. All arrays constant-indexed
// (full unroll) so nothing goes to scratch.
__global__ __launch_bounds__(64, 2) void k_stage1(const int* __restrict__ tokens,
    const float* __restrict__ T1, const float* __restrict__ b1v,
    const float* __restrict__ W3T, const float* __restrict__ bias3T,
    float* __restrict__ hbuf) {
  const int lane = threadIdx.x;          // 64-thread block = 1 wave
#pragma unroll 1
  for (int b = 0; b < 2; ++b) {
    const int item = (blockIdx.x * 2 + b) * 64 + lane;
    const int* tp = tokens + (size_t)item * 10;
    int tok[10];
#pragma unroll
    for (int l = 0; l < 10; ++l) tok[l] = tp[l];

    // gather-sum 10 T1 rows (each 64 floats, 256B-aligned, lane-contiguous)
    float4 h[16];
    {
      const float4* r = (const float4*)(T1 + (size_t)tok[0] * 640);
#pragma unroll
      for (int c = 0; c < 16; ++c) h[c] = r[c];
    }
#pragma unroll
    for (int l = 1; l < 10; ++l) {
      const float4* r = (const float4*)(T1 + (size_t)tok[l] * 640 + l * 64);
#pragma unroll
      for (int c = 0; c < 16; ++c) {
        float4 v = r[c];
        h[c].x += v.x; h[c].y += v.y; h[c].z += v.z; h[c].w += v.w;
      }
    }
    // + bias, relu  (b1v wave-uniform -> s_load)
    float h1[64];
    const float4* b1q = (const float4*)b1v;
#pragma unroll
    for (int c = 0; c < 16; ++c) {
      float4 bq = b1q[c];
      h1[4 * c]     = fmaxf(h[c].x + bq.x, 0.f);
      h1[4 * c + 1] = fmaxf(h[c].y + bq.y, 0.f);
      h1[4 * c + 2] = fmaxf(h[c].z + bq.z, 0.f);
      h1[4 * c + 3] = fmaxf(h[c].w + bq.w, 0.f);
    }

    // gates: 3 chunks (i, g, o), 16 outputs each; weights via SGPR stream
    float acti[16], actg[16], acto[16];
#pragma unroll
    for (int ch = 0; ch < 3; ++ch) {
      float acc[16];
#pragma unroll
      for (int j = 0; j < 16; ++j) acc[j] = bias3T[ch * 16 + j];
#pragma unroll
      for (int k = 0; k < 64; ++k) {
        const float hk = h1[k];
#pragma unroll
        for (int j = 0; j < 16; ++j)
          acc[j] = fmaf(W3T[k * 48 + ch * 16 + j], hk, acc[j]);
      }
#pragma unroll
      for (int j = 0; j < 16; ++j) {
        float x = acc[j];
        float a;
        if (ch == 1) {   // tanh
          float e = __expf(-2.f * x);
          a = fmaf(2.f, __builtin_amdgcn_rcpf(1.f + e), -1.f);
        } else {         // sigmoid
          float e = __expf(-x);
          a = __builtin_amdgcn_rcpf(1.f + e);
        }
        if (ch == 0) acti[j] = a;
        else if (ch == 1) actg[j] = a;
        else acto[j] = a;
      }
    }

    // h = sigmoid(o) * tanh(sigmoid(i)*tanh(g)); store 64B per lane
    float res[16];
#pragma unroll
    for (int j = 0; j < 16; ++j) {
      float c = acti[j] * actg[j];
      float e2 = __expf(-2.f * c);
      float th = fmaf(2.f, __builtin_amdgcn_rcpf(1.f + e2), -1.f);
      res[j] = acto[j] * th;
    }
    float4* op = (float4*)(hbuf + (size_t)item * 16);
#pragma unroll
    for (int q = 0; q < 4; ++q)
      op[q] = make_float4(res[4 * q], res[4 * q + 1], res[4 * q + 2], res[4 * q + 3]);
  }
}

// ---------------- K2: per-tree: child_ff(h160) -> heads + s + M partials ----------------
__global__ __launch_bounds__(256) void k_stage2(const float* __restrict__ hbuf,
    const float* __restrict__ W1, const float* __restrict__ b1v,
    const float* __restrict__ W2, const float* __restrict__ b2v,
    const float* __restrict__ fmW, const float* __restrict__ fmb,
    const float* __restrict__ tsW, const float* __restrict__ tsb,
    const float* __restrict__ suW, const float* __restrict__ sub_b,
    float* __restrict__ out, float* __restrict__ partials) {
  __shared__ float h1b_lds[32 * 68];
  __shared__ float code_lds[32 * 20];
  __shared__ float ff_lds[32 * 12];
  int tid = threadIdx.x;
  int lane = tid & 63;
  int wid = __builtin_amdgcn_readfirstlane(tid >> 6);
  int treeBase = blockIdx.x * 32;
  {   // GEMM: wave computes 8 trees, lane = output o
    int tw = treeBase + wid * 8;
    float acc[8];
#pragma unroll
    for (int t = 0; t < 8; ++t) acc[t] = b1v[lane];
    const float* wrow = W1 + lane * 160;
    const float* xbase = hbuf + (size_t)tw * 160;
    for (int k = 0; k < 160; k += 4) {
      float4 wv = *(const float4*)(wrow + k);
#pragma unroll
      for (int t = 0; t < 8; ++t) {
        float4 xv = *(const float4*)(xbase + t * 160 + k);  // wave-uniform -> s_load
        acc[t] = fmaf(wv.x, xv.x, acc[t]);
        acc[t] = fmaf(wv.y, xv.y, acc[t]);
        acc[t] = fmaf(wv.z, xv.z, acc[t]);
        acc[t] = fmaf(wv.w, xv.w, acc[t]);
      }
    }
#pragma unroll
    for (int t = 0; t < 8; ++t)
      h1b_lds[(wid * 8 + t) * 68 + lane] = fmaxf(acc[t], 0.f);
  }
  __syncthreads();
  {   // code = W2 @ relu(h1b) + b2 : thread -> (tree t2, outputs jj, jj+8)
    int t2 = tid >> 3, jj = tid & 7;
    float c0 = b2v[jj], c1 = b2v[jj + 8];
    const float* w2a = W2 + jj * 64;
    const float* w2b = W2 + (jj + 8) * 64;
    const float* hb = &h1b_lds[t2 * 68];
    for (int o = 0; o < 64; o += 4) {
      float4 hv = *(const float4*)(hb + o);
      float4 a4 = *(const float4*)(w2a + o);
      float4 b4 = *(const float4*)(w2b + o);
      c0 = fmaf(a4.x, hv.x, c0); c0 = fmaf(a4.y, hv.y, c0);
      c0 = fmaf(a4.z, hv.z, c0); c0 = fmaf(a4.w, hv.w, c0);
      c1 = fmaf(b4.x, hv.x, c1); c1 = fmaf(b4.y, hv.y, c1);
      c1 = fmaf(b4.z, hv.z, c1); c1 = fmaf(b4.w, hv.w, c1);
    }
    code_lds[t2 * 20 + jj] = c0;
    code_lds[t2 * 20 + jj + 8] = c1;
  }
  __syncthreads();
  {   // ff_out = fmW @ code + fmb
    int t = tid >> 3, q = tid & 7;
    float f = fmb[q];
    const float* cw = fmW + q * 16;
    const float* cl = &code_lds[t * 20];
#pragma unroll
    for (int j4 = 0; j4 < 16; j4 += 4) {
      float4 cv = *(const float4*)(cl + j4);
      float4 wv = *(const float4*)(cw + j4);
      f = fmaf(wv.x, cv.x, f); f = fmaf(wv.y, cv.y, f);
      f = fmaf(wv.z, cv.z, f); f = fmaf(wv.w, cv.w, f);
    }
    ff_lds[t * 12 + q] = f;
  }
  __syncthreads();
  {   // s (unnormalized) to d_out; score for tid<32
    int t = tid >> 3, r = tid & 7;
    float4 f0 = *(const float4*)&ff_lds[t * 12];
    float4 f1 = *(const float4*)&ff_lds[t * 12 + 4];
    int tree = treeBase + t;
    float* od = out + (size_t)BB + (size_t)tree * 128 + r * 16;
#pragma unroll
    for (int cc = 0; cc < 16; ++cc) {
      int c = r * 16 + cc;
      const float* u = suW + c * 8;
      float4 u0 = *(const float4*)(u);
      float4 u1 = *(const float4*)(u + 4);
      float sv = sub_b[c];
      sv = fmaf(u0.x, f0.x, sv); sv = fmaf(u0.y, f0.y, sv);
      sv = fmaf(u0.z, f0.z, sv); sv = fmaf(u0.w, f0.w, sv);
      sv = fmaf(u1.x, f1.x, sv); sv = fmaf(u1.y, f1.y, sv);
      sv = fmaf(u1.z, f1.z, sv); sv = fmaf(u1.w, f1.w, sv);
      od[cc] = sv;
    }
    if (tid < 32) {
      int tt = tid;
      float4 g0 = *(const float4*)&ff_lds[tt * 12];
      float4 g1 = *(const float4*)&ff_lds[tt * 12 + 4];
      float sc = tsb[0];
      sc = fmaf(tsW[0], g0.x, sc); sc = fmaf(tsW[1], g0.y, sc);
      sc = fmaf(tsW[2], g0.z, sc); sc = fmaf(tsW[3], g0.w, sc);
      sc = fmaf(tsW[4], g1.x, sc); sc = fmaf(tsW[5], g1.y, sc);
      sc = fmaf(tsW[6], g1.z, sc); sc = fmaf(tsW[7], g1.w, sc);
      out[treeBase + tt] = tanhf(sc);
    }
  }
  {   // per-wave 9x9 second-moment partials over its 8 trees (f9 = [ff_out, 1])
    int waveId = blockIdx.x * 4 + wid;
    float* pw = partials + (size_t)waveId * 88;
#pragma unroll
    for (int rep = 0; rep < 2; ++rep) {
      int e = lane + rep * 64;
      if (e < 81) {
        int i = e / 9, jx = e - i * 9;
        float m = 0.f;
#pragma unroll
        for (int t = 0; t < 8; ++t) {
          const float* fr = &ff_lds[(wid * 8 + t) * 12];
          float fi = (i  < 8) ? fr[i]  : 1.f;
          float fj = (jx < 8) ? fr[jx] : 1.f;
          m = fmaf(fi, fj, m);
        }
        pw[e] = m;
      }
    }
  }
}

// ---------------- K3a: reduce M partials (4096 waves) in f64 ----------------
__global__ __launch_bounds__(256) void k_reduce(const float* __restrict__ partials,
                                                double* __restrict__ Msum) {
  __shared__ double red[256];
  int e = blockIdx.x;    // 0..80
  double s = 0.0;
  for (int w = threadIdx.x; w < 4096; w += 256)
    s += (double)partials[(size_t)w * 88 + e];
  red[threadIdx.x] = s;
  __syncthreads();
  for (int off = 128; off > 0; off >>= 1) {
    if (threadIdx.x < off) red[threadIdx.x] += red[threadIdx.x + off];
    __syncthreads();
  }
  if (threadIdx.x == 0) Msum[e] = red[0];
}

// ---------------- K3b: per-column BN stats -> A[c], B[c] ----------------
__global__ __launch_bounds__(128) void k_stats(const double* __restrict__ Msum,
    const float* __restrict__ suW, const float* __restrict__ sub_b,
    const float* __restrict__ gamma, const float* __restrict__ beta,
    float* __restrict__ statsA, float* __restrict__ statsB) {
  int c = threadIdx.x;
  double u[9];
#pragma unroll
  for (int q = 0; q < 8; ++q) u[q] = (double)suW[c * 8 + q];
  u[8] = (double)sub_b[c];
  double S1 = 0.0;
#pragma unroll
  for (int i = 0; i < 9; ++i) S1 += u[i] * Msum[72 + i];   // row 8 of M = sums of f9
  double mu = S1 / (double)BB;
  double E2 = 0.0;
#pragma unroll
  for (int i = 0; i < 9; ++i) {
    double acc = 0.0;
#pragma unroll
    for (int jx = 0; jx < 9; ++jx) acc += u[jx] * Msum[i * 9 + jx];
    E2 += u[i] * acc;
  }
  E2 /= (double)BB;
  double var = E2 - mu * mu;
  if (var < 0.0) var = 0.0;
  double rs = 1.0 / sqrt(var + (double)EPSBN);
  double A = (double)gamma[c] * rs;
  statsA[c] = (float)A;
  statsB[c] = (float)((double)beta[c] - mu * A);
}

// ---------------- K4: in-place normalize summary region of d_out ----------------
__global__ __launch_bounds__(256) void k_norm(float* __restrict__ out,
    const float* __restrict__ statsA, const float* __restrict__ statsB) {
  int idx = blockIdx.x * 256 + threadIdx.x;   // 1,048,576 float4s
  float4* p = (float4*)(out + BB);
  float4 v = p[idx];
  int c4 = idx & 31;
  float4 a = ((const float4*)statsA)[c4];
  float4 b = ((const float4*)statsB)[c4];
  v.x = fmaf(v.x, a.x, b.x);
  v.y = fmaf(v.y, a.y, b.y);
  v.z = fmaf(v.z, a.z, b.z);
  v.w = fmaf(v.w, a.w, b.w);
  p[idx] = v;
}

extern "C" void kernel_launch(void* const* d_in, const int* in_sizes, int n_in,
                              void* d_out, int out_size, void* d_ws, size_t ws_size,
                              hipStream_t stream) {
  const int*   tokens = (const int*)d_in[0];
  const float* emb   = (const float*)d_in[1];
  const float* w_ih  = (const float*)d_in[2];
  const float* b_ih  = (const float*)d_in[3];
  const float* b_hh  = (const float*)d_in[4];
  const float* ffW1  = (const float*)d_in[5];
  const float* ffb1  = (const float*)d_in[6];
  const float* ffW2  = (const float*)d_in[7];
  const float* ffb2  = (const float*)d_in[8];
  const float* fmW   = (const float*)d_in[9];
  const float* fmb   = (const float*)d_in[10];
  const float* tsW   = (const float*)d_in[11];
  const float* tsb   = (const float*)d_in[12];
  const float* suW   = (const float*)d_in[13];
  const float* sub_b = (const float*)d_in[14];
  const float* gamma = (const float*)d_in[15];
  const float* beta  = (const float*)d_in[16];
  float* out = (float*)d_out;
  float* ws = (float*)d_ws;

  float*  T1       = ws;                               // 1,280,000 f
  float*  hbuf     = T1 + 1280000;                     // 5,242,880 f
  float*  partials = hbuf + 5242880;                   // 360,448 f
  double* Msum     = (double*)(partials + 360448);     // 81 d (8B aligned)
  float*  statsA   = (float*)(Msum + 82);              // 128 f (16B aligned)
  float*  statsB   = statsA + 128;                     // 128 f
  float*  W3T      = statsB + 128;                     // 3072 f
  float*  bias3T   = W3T + 3072;                       // 48 f

  hipLaunchKernelGGL(k_table,  dim3(5000), dim3(256), 0, stream, emb, ffW1, T1);
  hipLaunchKernelGGL(k_fuse,   dim3(13),   dim3(256), 0, stream,
                     w_ih, b_ih, b_hh, ffW2, ffb2, W3T, bias3T);
  hipLaunchKernelGGL(k_stage1, dim3(2560), dim3(64), 0, stream,
                     tokens, T1, ffb1, W3T, bias3T, hbuf);
  hipLaunchKernelGGL(k_stage2, dim3(1024), dim3(256), 0, stream,
                     hbuf, ffW1, ffb1, ffW2, ffb2, fmW, fmb, tsW, tsb, suW, sub_b,
                     out, partials);
  hipLaunchKernelGGL(k_reduce, dim3(81),   dim3(256), 0, stream, partials, Msum);
  hipLaunchKernelGGL(k_stats,  dim3(1),    dim3(128), 0, stream,
                     Msum, suW, sub_b, gamma, beta, statsA, statsB);
  hipLaunchKernelGGL(k_norm,   dim3(4096), dim3(256), 0, stream, out, statsA, statsB);
}

// Round 6
// 216.782 us; speedup vs baseline: 1.7716x; 1.7716x over previous
//
#include <hip/hip_runtime.h>
#include <hip/hip_bf16.h>

#define BB 32768
#define NN 10
#define VV 2000
#define EPSBN 1e-5

// ---------------- K0: build T1[v][l][o] = emb[v] . W1[o][16l:16l+16] ----------------
__global__ __launch_bounds__(256) void k_table(const float* __restrict__ emb,
                                               const float* __restrict__ W1,
                                               float* __restrict__ T1) {
  int idx = blockIdx.x * 256 + threadIdx.x;
  if (idx >= VV * 640) return;
  int v = idx / 640;
  int r = idx - v * 640;
  int l = r >> 6;
  int o = r & 63;
  const float* e = emb + v * 16;
  const float* w = W1 + o * 160 + l * 16;
  float s = 0.f;
#pragma unroll
  for (int k = 0; k < 16; ++k) s = fmaf(e[k], w[k], s);
  T1[idx] = s;
}

// ---- K0b: W3T[k][jj] = (w_ih @ W2) transposed, f-gate rows stripped ----
// jj in [0,48): 0-15 -> i rows, 16-31 -> g rows (w_ih row jj+16),
// 32-47 -> o rows (w_ih row jj+16). bias3T likewise. bias3T = W3T+3072 in ws.
__global__ __launch_bounds__(256) void k_fuse(const float* __restrict__ w_ih,
    const float* __restrict__ b_ih, const float* __restrict__ b_hh,
    const float* __restrict__ W2, const float* __restrict__ b2v,
    float* __restrict__ W3T, float* __restrict__ bias3T) {
  int idx = blockIdx.x * 256 + threadIdx.x;
  if (idx < 3072) {
    int k = idx / 48, jj = idx - k * 48;
    int gr = (jj < 16) ? jj : jj + 16;
    float s = 0.f;
#pragma unroll
    for (int o = 0; o < 16; ++o) s = fmaf(w_ih[gr * 16 + o], W2[o * 64 + k], s);
    W3T[idx] = s;
  } else if (idx < 3120) {
    int jj = idx - 3072;
    int gr = (jj < 16) ? jj : jj + 16;
    float s = b_ih[gr] + b_hh[gr];
#pragma unroll
    for (int o = 0; o < 16; ++o) s = fmaf(w_ih[gr * 16 + o], b2v[o], s);
    bias3T[jj] = s;
  }
}

// ---------------- K1: item-per-lane, weights via LDS broadcast ----------------
// Round-5 lessons: (a) SGPR weight-streaming stalls on lgkmcnt with only 96
// SGPRs; weights now staged once in LDS, read as broadcast ds_read_b128
// (768/wave amortized over 64 items = 12/item vs round-4's 16/item serialized
// per item). (b) 2560 waves = 2.5/SIMD exposed all latency; now 5120 waves
// (1 item/lane), 3 waves/SIMD at VGPR<=170. Gathers stay 16B/lane scattered
// (TA sweet spot). Full unroll keeps h1[64]/acc[48] constant-indexed.
__global__ __launch_bounds__(256, 3) void k_stage1(const int* __restrict__ tokens,
    const float* __restrict__ T1, const float* __restrict__ b1v,
    const float* __restrict__ W3T_and_bias,   // 3120 floats contiguous
    float* __restrict__ hbuf) {
  __shared__ __align__(16) float w_lds[3120];
  const int tid = threadIdx.x;
  for (int i = tid; i < 780; i += 256)
    ((float4*)w_lds)[i] = ((const float4*)W3T_and_bias)[i];

  const int item = blockIdx.x * 256 + tid;   // grid 1280*256 = 327680 items
  // tokens: 40B per item, 8B-aligned -> 5 int2 loads
  int tk[10];
  {
    const int2* tp2 = (const int2*)(tokens + (size_t)item * 10);
#pragma unroll
    for (int q = 0; q < 5; ++q) { int2 t = tp2[q]; tk[2 * q] = t.x; tk[2 * q + 1] = t.y; }
  }
  __syncthreads();   // w_lds ready (also drains token loads - needed anyway)

  // gather-sum 10 T1 rows (256B each, 16B/lane scattered reads)
  float4 h[16];
  {
    const float4* r = (const float4*)(T1 + (size_t)tk[0] * 640);
#pragma unroll
    for (int c = 0; c < 16; ++c) h[c] = r[c];
  }
#pragma unroll
  for (int l = 1; l < 10; ++l) {
    const float4* r = (const float4*)(T1 + (size_t)tk[l] * 640 + l * 64);
#pragma unroll
    for (int c = 0; c < 16; ++c) {
      float4 v = r[c];
      h[c].x += v.x; h[c].y += v.y; h[c].z += v.z; h[c].w += v.w;
    }
  }
  // + bias (wave-uniform -> s_load), relu
  float h1[64];
  {
    const float4* b1q = (const float4*)b1v;
#pragma unroll
    for (int c = 0; c < 16; ++c) {
      float4 bq = b1q[c];
      h1[4 * c]     = fmaxf(h[c].x + bq.x, 0.f);
      h1[4 * c + 1] = fmaxf(h[c].y + bq.y, 0.f);
      h1[4 * c + 2] = fmaxf(h[c].z + bq.z, 0.f);
      h1[4 * c + 3] = fmaxf(h[c].w + bq.w, 0.f);
    }
  }

  // gates: acc[0..15]=i, [16..31]=g, [32..47]=o; weights broadcast from LDS
  float acc[48];
#pragma unroll
  for (int j4 = 0; j4 < 12; ++j4) {
    float4 b = *(const float4*)&w_lds[3072 + j4 * 4];
    acc[4 * j4] = b.x; acc[4 * j4 + 1] = b.y; acc[4 * j4 + 2] = b.z; acc[4 * j4 + 3] = b.w;
  }
#pragma unroll
  for (int k = 0; k < 64; ++k) {
    const float hk = h1[k];
#pragma unroll
    for (int j4 = 0; j4 < 12; ++j4) {
      float4 w = *(const float4*)&w_lds[k * 48 + j4 * 4];
      acc[4 * j4]     = fmaf(w.x, hk, acc[4 * j4]);
      acc[4 * j4 + 1] = fmaf(w.y, hk, acc[4 * j4 + 1]);
      acc[4 * j4 + 2] = fmaf(w.z, hk, acc[4 * j4 + 2]);
      acc[4 * j4 + 3] = fmaf(w.w, hk, acc[4 * j4 + 3]);
    }
  }

  // activations + LSTM combine; h = sig(o) * tanh(sig(i)*tanh(g))
  float res[16];
#pragma unroll
  for (int j = 0; j < 16; ++j) {
    float si = __builtin_amdgcn_rcpf(1.f + __expf(-acc[j]));
    float tg = fmaf(2.f, __builtin_amdgcn_rcpf(1.f + __expf(-2.f * acc[16 + j])), -1.f);
    float so = __builtin_amdgcn_rcpf(1.f + __expf(-acc[32 + j]));
    float c = si * tg;
    float th = fmaf(2.f, __builtin_amdgcn_rcpf(1.f + __expf(-2.f * c)), -1.f);
    res[j] = so * th;
  }
  float4* op = (float4*)(hbuf + (size_t)item * 16);
#pragma unroll
  for (int q = 0; q < 4; ++q)
    op[q] = make_float4(res[4 * q], res[4 * q + 1], res[4 * q + 2], res[4 * q + 3]);
}

// ---------------- K2: per-tree: child_ff(h160) -> heads + s + M partials ----------------
__global__ __launch_bounds__(256) void k_stage2(const float* __restrict__ hbuf,
    const float* __restrict__ W1, const float* __restrict__ b1v,
    const float* __restrict__ W2, const float* __restrict__ b2v,
    const float* __restrict__ fmW, const float* __restrict__ fmb,
    const float* __restrict__ tsW, const float* __restrict__ tsb,
    const float* __restrict__ suW, const float* __restrict__ sub_b,
    float* __restrict__ out, float* __restrict__ partials) {
  __shared__ float h1b_lds[32 * 68];
  __shared__ float code_lds[32 * 20];
  __shared__ float ff_lds[32 * 12];
  int tid = threadIdx.x;
  int lane = tid & 63;
  int wid = __builtin_amdgcn_readfirstlane(tid >> 6);
  int treeBase = blockIdx.x * 32;
  {   // GEMM: wave computes 8 trees, lane = output o
    int tw = treeBase + wid * 8;
    float acc[8];
#pragma unroll
    for (int t = 0; t < 8; ++t) acc[t] = b1v[lane];
    const float* wrow = W1 + lane * 160;
    const float* xbase = hbuf + (size_t)tw * 160;
    for (int k = 0; k < 160; k += 4) {
      float4 wv = *(const float4*)(wrow + k);
#pragma unroll
      for (int t = 0; t < 8; ++t) {
        float4 xv = *(const float4*)(xbase + t * 160 + k);  // wave-uniform -> s_load
        acc[t] = fmaf(wv.x, xv.x, acc[t]);
        acc[t] = fmaf(wv.y, xv.y, acc[t]);
        acc[t] = fmaf(wv.z, xv.z, acc[t]);
        acc[t] = fmaf(wv.w, xv.w, acc[t]);
      }
    }
#pragma unroll
    for (int t = 0; t < 8; ++t)
      h1b_lds[(wid * 8 + t) * 68 + lane] = fmaxf(acc[t], 0.f);
  }
  __syncthreads();
  {   // code = W2 @ relu(h1b) + b2 : thread -> (tree t2, outputs jj, jj+8)
    int t2 = tid >> 3, jj = tid & 7;
    float c0 = b2v[jj], c1 = b2v[jj + 8];
    const float* w2a = W2 + jj * 64;
    const float* w2b = W2 + (jj + 8) * 64;
    const float* hb = &h1b_lds[t2 * 68];
    for (int o = 0; o < 64; o += 4) {
      float4 hv = *(const float4*)(hb + o);
      float4 a4 = *(const float4*)(w2a + o);
      float4 b4 = *(const float4*)(w2b + o);
      c0 = fmaf(a4.x, hv.x, c0); c0 = fmaf(a4.y, hv.y, c0);
      c0 = fmaf(a4.z, hv.z, c0); c0 = fmaf(a4.w, hv.w, c0);
      c1 = fmaf(b4.x, hv.x, c1); c1 = fmaf(b4.y, hv.y, c1);
      c1 = fmaf(b4.z, hv.z, c1); c1 = fmaf(b4.w, hv.w, c1);
    }
    code_lds[t2 * 20 + jj] = c0;
    code_lds[t2 * 20 + jj + 8] = c1;
  }
  __syncthreads();
  {   // ff_out = fmW @ code + fmb
    int t = tid >> 3, q = tid & 7;
    float f = fmb[q];
    const float* cw = fmW + q * 16;
    const float* cl = &code_lds[t * 20];
#pragma unroll
    for (int j4 = 0; j4 < 16; j4 += 4) {
      float4 cv = *(const float4*)(cl + j4);
      float4 wv = *(const float4*)(cw + j4);
      f = fmaf(wv.x, cv.x, f); f = fmaf(wv.y, cv.y, f);
      f = fmaf(wv.z, cv.z, f); f = fmaf(wv.w, cv.w, f);
    }
    ff_lds[t * 12 + q] = f;
  }
  __syncthreads();
  {   // s (unnormalized) to d_out; score for tid<32
    int t = tid >> 3, r = tid & 7;
    float4 f0 = *(const float4*)&ff_lds[t * 12];
    float4 f1 = *(const float4*)&ff_lds[t * 12 + 4];
    int tree = treeBase + t;
    float* od = out + (size_t)BB + (size_t)tree * 128 + r * 16;
#pragma unroll
    for (int cc = 0; cc < 16; ++cc) {
      int c = r * 16 + cc;
      const float* u = suW + c * 8;
      float4 u0 = *(const float4*)(u);
      float4 u1 = *(const float4*)(u + 4);
      float sv = sub_b[c];
      sv = fmaf(u0.x, f0.x, sv); sv = fmaf(u0.y, f0.y, sv);
      sv = fmaf(u0.z, f0.z, sv); sv = fmaf(u0.w, f0.w, sv);
      sv = fmaf(u1.x, f1.x, sv); sv = fmaf(u1.y, f1.y, sv);
      sv = fmaf(u1.z, f1.z, sv); sv = fmaf(u1.w, f1.w, sv);
      od[cc] = sv;
    }
    if (tid < 32) {
      int tt = tid;
      float4 g0 = *(const float4*)&ff_lds[tt * 12];
      float4 g1 = *(const float4*)&ff_lds[tt * 12 + 4];
      float sc = tsb[0];
      sc = fmaf(tsW[0], g0.x, sc); sc = fmaf(tsW[1], g0.y, sc);
      sc = fmaf(tsW[2], g0.z, sc); sc = fmaf(tsW[3], g0.w, sc);
      sc = fmaf(tsW[4], g1.x, sc); sc = fmaf(tsW[5], g1.y, sc);
      sc = fmaf(tsW[6], g1.z, sc); sc = fmaf(tsW[7], g1.w, sc);
      out[treeBase + tt] = tanhf(sc);
    }
  }
  {   // per-wave 9x9 second-moment partials over its 8 trees (f9 = [ff_out, 1])
    int waveId = blockIdx.x * 4 + wid;
    float* pw = partials + (size_t)waveId * 88;
#pragma unroll
    for (int rep = 0; rep < 2; ++rep) {
      int e = lane + rep * 64;
      if (e < 81) {
        int i = e / 9, jx = e - i * 9;
        float m = 0.f;
#pragma unroll
        for (int t = 0; t < 8; ++t) {
          const float* fr = &ff_lds[(wid * 8 + t) * 12];
          float fi = (i  < 8) ? fr[i]  : 1.f;
          float fj = (jx < 8) ? fr[jx] : 1.f;
          m = fmaf(fi, fj, m);
        }
        pw[e] = m;
      }
    }
  }
}

// ---------------- K3a: reduce M partials (4096 waves) in f64 ----------------
__global__ __launch_bounds__(256) void k_reduce(const float* __restrict__ partials,
                                                double* __restrict__ Msum) {
  __shared__ double red[256];
  int e = blockIdx.x;    // 0..80
  double s = 0.0;
  for (int w = threadIdx.x; w < 4096; w += 256)
    s += (double)partials[(size_t)w * 88 + e];
  red[threadIdx.x] = s;
  __syncthreads();
  for (int off = 128; off > 0; off >>= 1) {
    if (threadIdx.x < off) red[threadIdx.x] += red[threadIdx.x + off];
    __syncthreads();
  }
  if (threadIdx.x == 0) Msum[e] = red[0];
}

// ---------------- K3b: per-column BN stats -> A[c], B[c] ----------------
__global__ __launch_bounds__(128) void k_stats(const double* __restrict__ Msum,
    const float* __restrict__ suW, const float* __restrict__ sub_b,
    const float* __restrict__ gamma, const float* __restrict__ beta,
    float* __restrict__ statsA, float* __restrict__ statsB) {
  int c = threadIdx.x;
  double u[9];
#pragma unroll
  for (int q = 0; q < 8; ++q) u[q] = (double)suW[c * 8 + q];
  u[8] = (double)sub_b[c];
  double S1 = 0.0;
#pragma unroll
  for (int i = 0; i < 9; ++i) S1 += u[i] * Msum[72 + i];   // row 8 of M = sums of f9
  double mu = S1 / (double)BB;
  double E2 = 0.0;
#pragma unroll
  for (int i = 0; i < 9; ++i) {
    double acc = 0.0;
#pragma unroll
    for (int jx = 0; jx < 9; ++jx) acc += u[jx] * Msum[i * 9 + jx];
    E2 += u[i] * acc;
  }
  E2 /= (double)BB;
  double var = E2 - mu * mu;
  if (var < 0.0) var = 0.0;
  double rs = 1.0 / sqrt(var + (double)EPSBN);
  double A = (double)gamma[c] * rs;
  statsA[c] = (float)A;
  statsB[c] = (float)((double)beta[c] - mu * A);
}

// ---------------- K4: in-place normalize summary region of d_out ----------------
__global__ __launch_bounds__(256) void k_norm(float* __restrict__ out,
    const float* __restrict__ statsA, const float* __restrict__ statsB) {
  int idx = blockIdx.x * 256 + threadIdx.x;   // 1,048,576 float4s
  float4* p = (float4*)(out + BB);
  float4 v = p[idx];
  int c4 = idx & 31;
  float4 a = ((const float4*)statsA)[c4];
  float4 b = ((const float4*)statsB)[c4];
  v.x = fmaf(v.x, a.x, b.x);
  v.y = fmaf(v.y, a.y, b.y);
  v.z = fmaf(v.z, a.z, b.z);
  v.w = fmaf(v.w, a.w, b.w);
  p[idx] = v;
}

extern "C" void kernel_launch(void* const* d_in, const int* in_sizes, int n_in,
                              void* d_out, int out_size, void* d_ws, size_t ws_size,
                              hipStream_t stream) {
  const int*   tokens = (const int*)d_in[0];
  const float* emb   = (const float*)d_in[1];
  const float* w_ih  = (const float*)d_in[2];
  const float* b_ih  = (const float*)d_in[3];
  const float* b_hh  = (const float*)d_in[4];
  const float* ffW1  = (const float*)d_in[5];
  const float* ffb1  = (const float*)d_in[6];
  const float* ffW2  = (const float*)d_in[7];
  const float* ffb2  = (const float*)d_in[8];
  const float* fmW   = (const float*)d_in[9];
  const float* fmb   = (const float*)d_in[10];
  const float* tsW   = (const float*)d_in[11];
  const float* tsb   = (const float*)d_in[12];
  const float* suW   = (const float*)d_in[13];
  const float* sub_b = (const float*)d_in[14];
  const float* gamma = (const float*)d_in[15];
  const float* beta  = (const float*)d_in[16];
  float* out = (float*)d_out;
  float* ws = (float*)d_ws;

  float*  T1       = ws;                               // 1,280,000 f
  float*  hbuf     = T1 + 1280000;                     // 5,242,880 f
  float*  partials = hbuf + 5242880;                   // 360,448 f
  double* Msum     = (double*)(partials + 360448);     // 81 d (8B aligned)
  float*  statsA   = (float*)(Msum + 82);              // 128 f (16B aligned)
  float*  statsB   = statsA + 128;                     // 128 f
  float*  W3T      = statsB + 128;                     // 3072 f (16B aligned)
  float*  bias3T   = W3T + 3072;                       // 48 f (contiguous with W3T)

  hipLaunchKernelGGL(k_table,  dim3(5000), dim3(256), 0, stream, emb, ffW1, T1);
  hipLaunchKernelGGL(k_fuse,   dim3(13),   dim3(256), 0, stream,
                     w_ih, b_ih, b_hh, ffW2, ffb2, W3T, bias3T);
  hipLaunchKernelGGL(k_stage1, dim3(1280), dim3(256), 0, stream,
                     tokens, T1, ffb1, W3T, hbuf);
  hipLaunchKernelGGL(k_stage2, dim3(1024), dim3(256), 0, stream,
                     hbuf, ffW1, ffb1, ffW2, ffb2, fmW, fmb, tsW, tsb, suW, sub_b,
                     out, partials);
  hipLaunchKernelGGL(k_reduce, dim3(81),   dim3(256), 0, stream, partials, Msum);
  hipLaunchKernelGGL(k_stats,  dim3(1),    dim3(128), 0, stream,
                     Msum, suW, sub_b, gamma, beta, statsA, statsB);
  hipLaunchKernelGGL(k_norm,   dim3(4096), dim3(256), 0, stream, out, statsA, statsB);
}